// Round 13
// baseline (1803.229 us; speedup 1.0000x reference)
//
#include <hip/hip_runtime.h>
#include <math.h>

#define SA 68    // stride (floats) for [16][64] block-shared buffers
#define SX 132   // stride for [16][128] buffers
#define SW 66    // stride for per-wave [16][64] buffers

// LDS pool offsets (floats)
#define P_H   0        // 1088 residual h
#define P_Z   1088     // 1088 transformer stream
#define P_A   2176     // 1088 LN out (alias: conv temp)
#define P_FH  3264     // 2112 c11-out / watt / ff-half / res
#define P_CX  5376     // 1024 conv branch [c][l]
#define P_WQ  6400     // 4*1056 per-wave q  (alias: x^T, concat in [0..2112))
#define P_WK  10624    // 4*1056 per-wave k  (alias: attn out o)
#define P_WV  14848    // 4*1056 per-wave v
#define POOLF 19072    // 76288 B -> 2 blocks/CU

__device__ __forceinline__ float lrelu_f(float v){ return v > 0.f ? v : 0.01f*v; }
__device__ __forceinline__ float gelu_f(float v){ return 0.5f*v*(1.f + erff(v*0.70710678118654752f)); }
__device__ __forceinline__ void wave_sync(){ asm volatile("s_waitcnt lgkmcnt(0)" ::: "memory"); }

// block-wide GEMM (verified R5 core): out[l][d] = act(in[l][:] @ W[d][:]^T + b)
template<int ND, int K, int WS, int IS, int OS, int UNR>
__device__ __forceinline__ void gemm_nd(const float* __restrict__ in,
                                        const float* __restrict__ W,
                                        const float* __restrict__ bias,
                                        float* __restrict__ outp,
                                        int tid, int act, bool accum)
{
    const int l  = tid & 15;
    const int dq = tid >> 4;
    float acc[ND][4];
#pragma unroll
    for (int nb = 0; nb < ND; ++nb)
#pragma unroll
        for (int dd = 0; dd < 4; ++dd) acc[nb][dd] = 0.f;
    const float* inrow = in + l*IS;
    const float* wbase = W + (size_t)dq*4*WS;
#pragma unroll 1
    for (int k0 = 0; k0 < K; k0 += UNR*4) {
#pragma unroll
        for (int u = 0; u < UNR; ++u) {
            const int k = k0 + u*4;
            const float4 a4 = *(const float4*)(inrow + k);
#pragma unroll
            for (int nb = 0; nb < ND; ++nb) {
#pragma unroll
                for (int dd = 0; dd < 4; ++dd) {
                    const float4 w4 = *(const float4*)(wbase + (size_t)(nb*64 + dd)*WS + k);
                    acc[nb][dd] += w4.x*a4.x + w4.y*a4.y + w4.z*a4.z + w4.w*a4.w;
                }
            }
        }
    }
#pragma unroll
    for (int nb = 0; nb < ND; ++nb)
#pragma unroll
        for (int dd = 0; dd < 4; ++dd) {
            const int d = nb*64 + dq*4 + dd;
            float v = acc[nb][dd] + (bias ? bias[d] : 0.f);
            if (act == 1) v = v > 0.f ? v : 0.f;
            else if (act == 2) v = gelu_f(v);
            float* o = outp + l*OS + d;
            if (accum) *o += v; else *o = v;
        }
}

// per-wave GEMM: lane (l=lane&15, dq=lane>>4); out cols cq*16+dq*4+dd, K=64
template<int WS>
__device__ __forceinline__ void wgemm64(const float* __restrict__ arow,
                                        const float* __restrict__ wb,
                                        const float* __restrict__ bb,
                                        float* __restrict__ outrow, int dq)
{
#pragma unroll
    for (int cq = 0; cq < 4; ++cq) {
        float acc[4] = {0.f, 0.f, 0.f, 0.f};
#pragma unroll 1
        for (int k0 = 0; k0 < 64; k0 += 8) {
#pragma unroll
            for (int u = 0; u < 2; ++u) {
                const int k = k0 + u*4;
                const float4 a4 = *(const float4*)(arow + k);
#pragma unroll
                for (int dd = 0; dd < 4; ++dd) {
                    const float4 w4 = *(const float4*)(wb + (size_t)(cq*16 + dq*4 + dd)*WS + k);
                    acc[dd] += w4.x*a4.x + w4.y*a4.y + w4.z*a4.z + w4.w*a4.w;
                }
            }
        }
#pragma unroll
        for (int dd = 0; dd < 4; ++dd) {
            const int c = cq*16 + dq*4 + dd;
            outrow[c] = acc[dd] + (bb ? bb[c] : 0.f);
        }
    }
}

// LayerNorm 16x64 (stride SA); roll: src row r -> dst row (r+8)&15
__device__ __forceinline__ void ln16x64(const float* __restrict__ in,
                                        float* __restrict__ outb,
                                        const float* __restrict__ g, const float* __restrict__ bvec,
                                        int tid, bool roll)
{
    const int r = tid >> 4, c0 = (tid & 15) * 4;
    const float4 v = *(const float4*)(in + r*SA + c0);
    float s  = v.x + v.y + v.z + v.w;
    float sq = v.x*v.x + v.y*v.y + v.z*v.z + v.w*v.w;
#pragma unroll
    for (int m = 1; m < 16; m <<= 1) { s += __shfl_xor(s, m, 64); sq += __shfl_xor(sq, m, 64); }
    const float mean = s * (1.f/64.f);
    const float var  = sq * (1.f/64.f) - mean*mean;
    const float rstd = rsqrtf(var + 1e-5f);
    const int rd = roll ? ((r + 8) & 15) : r;
    const float4 gv = *(const float4*)(g + c0);
    const float4 bv = *(const float4*)(bvec + c0);
    float4 o;
    o.x = (v.x-mean)*rstd*gv.x + bv.x;
    o.y = (v.y-mean)*rstd*gv.y + bv.y;
    o.z = (v.z-mean)*rstd*gv.z + bv.z;
    o.w = (v.w-mean)*rstd*gv.w + bv.w;
    *(float4*)(outb + rd*SA + c0) = o;
}

// width-3 conv over L=16, zero pad, leaky-relu. layouts [ch][16].
__device__ __forceinline__ void conv3_lrelu(const float* __restrict__ in,
                                            float* __restrict__ outb,
                                            const float* __restrict__ w, const float* __restrict__ bias,
                                            int tid, int mode, float* __restrict__ cxbuf)
{
    const int o = tid >> 2, l0 = (tid & 3) * 4;
    float acc[4] = {0.f, 0.f, 0.f, 0.f};
    const float* wr0 = w + (size_t)o*64*3;
#pragma unroll 4
    for (int i = 0; i < 64; ++i) {
        const float* wr = wr0 + i*3;
        const float w0 = wr[0], w1 = wr[1], w2 = wr[2];
        const float* row = in + i*16 + l0;
        const float xm1 = (l0 == 0)  ? 0.f : row[-1];
        const float x0 = row[0], x1 = row[1], x2 = row[2], x3 = row[3];
        const float xp1 = (l0 == 12) ? 0.f : row[4];
        acc[0] += w0*xm1 + w1*x0 + w2*x1;
        acc[1] += w0*x0  + w1*x1 + w2*x2;
        acc[2] += w0*x1  + w1*x2 + w2*x3;
        acc[3] += w0*x2  + w1*x3 + w2*xp1;
    }
    const float bb = bias[o];
    if (mode == 0) {
#pragma unroll
        for (int j = 0; j < 4; ++j) outb[o*16 + l0 + j] = lrelu_f(acc[j] + bb);
    } else {
#pragma unroll
        for (int j = 0; j < 4; ++j) {
            float* p = cxbuf + o*16 + l0 + j;
            *p = lrelu_f(acc[j] + bb) + 2.f * (*p);
        }
    }
}

__global__ __launch_bounds__(256) void vse_fused(
    const float* __restrict__ x,
    const float* __restrict__ c11_w, const float* __restrict__ c11_b,
    const float* __restrict__ c12_w, const float* __restrict__ c12_b,
    const float* __restrict__ lse1_w, const float* __restrict__ lse1_b,
    const float* __restrict__ lse2_w, const float* __restrict__ lse2_b,
    const float* __restrict__ ln1_g, const float* __restrict__ ln1_b,
    const float* __restrict__ ln2_g, const float* __restrict__ ln2_b,
    const float* __restrict__ mlp1_w, const float* __restrict__ mlp1_b,
    const float* __restrict__ mlp2_w, const float* __restrict__ mlp2_b,
    const float* __restrict__ aln_g, const float* __restrict__ aln_b,
    const float* __restrict__ qkv_w, const float* __restrict__ qkv_b,
    const float* __restrict__ proj_w, const float* __restrict__ proj_b,
    const float* __restrict__ relpos,
    const float* __restrict__ fln_g, const float* __restrict__ fln_b,
    const float* __restrict__ ff1_w, const float* __restrict__ ff1_b,
    const float* __restrict__ ff2_w, const float* __restrict__ ff2_b,
    float* __restrict__ out)
{
    __shared__ float pool[POOLF];
    float* const s_h   = pool + P_H;
    float* const s_z   = pool + P_Z;
    float* const s_a   = pool + P_A;
    float* const s_fh  = pool + P_FH;
    float* const s_cx  = pool + P_CX;
    float* const s_xt  = pool + P_WQ;    // phase 0 alias (2112 <= 4224)
    float* const s_y   = s_fh;           // c11 out
    float* const s_t1  = s_a;            // conv temp
    float* const s_cat = pool + P_WQ;    // final concat
    float* const s_res = s_fh;           // final res

    const int tid  = threadIdx.x;
    const int lane = tid & 63;
    const int wv   = tid >> 6;           // wave id 0..3
    const int b = blockIdx.x;
    const float* xb = x + (size_t)b * 2048;

    float* const wq  = pool + P_WQ + wv*1056;   // this wave's q / proj-partial
    float* const wk  = pool + P_WK + wv*1056;   // this wave's k / attn-out o
    float* const wvv = pool + P_WV + wv*1056;   // this wave's v
    float* const watt = s_fh + wv*272;          // this wave's att probs [16][17]

    // ---- load x transposed ----
#pragma unroll
    for (int it = 0; it < 8; ++it) {
        const int idx = tid + it*256;           // = c*16 + l
        const int c = idx >> 4, l = idx & 15;
        s_xt[l*SX + c] = xb[idx];
    }
    __syncthreads();

    // ---- c11 (128x128 matmul) + relu ----
    gemm_nd<2,128,128,SX,SX,2>(s_xt, c11_w, c11_b, s_y, tid, 1, false);
    __syncthreads();

    // ---- split: conv_x [c][l], h [l][d] ----
#pragma unroll
    for (int it = 0; it < 4; ++it) {
        const int idx = tid + it*256;
        const int i = idx & 63, l = idx >> 6;
        s_cx[i*16 + l] = s_y[l*SX + i];
        s_h [l*SA + i] = s_y[l*SX + 64 + i];
    }
    __syncthreads();

    // ---- conv branch ----
    conv3_lrelu(s_cx, s_t1, lse1_w, lse1_b, tid, 0, nullptr);
    __syncthreads();
    conv3_lrelu(s_t1, nullptr, lse2_w, lse2_b, tid, 1, s_cx);
    __syncthreads();

    // ---- z = LN(h, ln1) ----
    ln16x64(s_h, s_z, ln1_g, ln1_b, tid, false);
    __syncthreads();

    // ---- transformer layers ----
    for (int layer = 0; layer < 2; ++layer) {
        const float* qkv_wl  = qkv_w + (size_t)layer * 98304;
        const float* qkv_bl  = qkv_b + layer * 1536;
        const float* proj_wl = proj_w + (size_t)layer * 32768;
        const float* proj_bl = proj_b + layer * 64;
        const float* rel_l   = relpos + layer * 8 * 49;

        // a = roll(LN(z, aln), -8)
        ln16x64(s_z, s_a, aln_g + layer*64, aln_b + layer*64, tid, true);
        __syncthreads();

        // ---- attention: one wave per head, 2 passes of 4 heads ----
        const int l  = lane & 15;
        const int dq = lane >> 4;        // 0..3
        for (int pass = 0; pass < 2; ++pass) {
            const int hh = pass*4 + wv;

            // QKV for this head (wave-local)
            const float* arow = s_a + l*SA;
            wgemm64<64>(arow, qkv_wl + (size_t)(hh*64)*64,          qkv_bl + hh*64,          wq  + l*SW, dq);
            wgemm64<64>(arow, qkv_wl + (size_t)(512 + hh*64)*64,    qkv_bl + 512 + hh*64,    wk  + l*SW, dq);
            wgemm64<64>(arow, qkv_wl + (size_t)(1024 + hh*64)*64,   qkv_bl + 1024 + hh*64,   wvv + l*SW, dq);
            wave_sync();

            // dots + relpos + mask + softmax: lane = i4*16 + j, rows i = i4*4+r
            {
                const int j = lane & 15, i4 = lane >> 4;
                float att_r[4];
#pragma unroll
                for (int r = 0; r < 4; ++r) {
                    const int i = i4*4 + r;
                    const float* qi = wq + i*SW;
                    const float* kj = wk + j*SW;
                    float dot = 0.f;
#pragma unroll 4
                    for (int d0 = 0; d0 < 64; d0 += 4) {
                        const float4 qv = *(const float4*)(qi + d0);
                        const float4 kv = *(const float4*)(kj + d0);
                        dot += qv.x*kv.x + qv.y*kv.y + qv.z*kv.z + qv.w*kv.w;
                    }
                    float val = dot * 0.125f
                              + rel_l[hh*49 + ((i>>2) - (j>>2) + 3)*7 + ((i&3) - (j&3) + 3)];
                    const bool masked = ((hh >= 6) && (((i>>2) < 2) != ((j>>2) < 2)))
                                     || ((hh & 1) && (((i&3) < 2) != ((j&3) < 2)));
                    if (masked) val = -1e9f;
                    att_r[r] = val;
                }
#pragma unroll
                for (int r = 0; r < 4; ++r) {
                    float mx = att_r[r];
#pragma unroll
                    for (int m = 1; m < 16; m <<= 1) mx = fmaxf(mx, __shfl_xor(mx, m, 64));
                    const float e = expf(att_r[r] - mx);
                    float ssum = e;
#pragma unroll
                    for (int m = 1; m < 16; m <<= 1) ssum += __shfl_xor(ssum, m, 64);
                    watt[(i4*4 + r)*17 + j] = e / ssum;
                }
            }
            wave_sync();

            // AV: o[l][c] = sum_j att[l][j] * v[j][c]; o -> wk (k dead)
            {
                float o16[4][4];
#pragma unroll
                for (int cq = 0; cq < 4; ++cq)
#pragma unroll
                    for (int dd = 0; dd < 4; ++dd) o16[cq][dd] = 0.f;
#pragma unroll 4
                for (int j = 0; j < 16; ++j) {
                    const float at = watt[l*17 + j];
                    const float* vr = wvv + j*SW + dq*4;
#pragma unroll
                    for (int cq = 0; cq < 4; ++cq) {
                        const float4 v4 = *(const float4*)(vr + cq*16);
                        o16[cq][0] += at*v4.x; o16[cq][1] += at*v4.y;
                        o16[cq][2] += at*v4.z; o16[cq][3] += at*v4.w;
                    }
                }
                wave_sync();   // ensure all att reads done before overwriting? (wk!=watt; ordering for wk write vs k reads already past)
#pragma unroll
                for (int cq = 0; cq < 4; ++cq) {
                    float4 o4; o4.x = o16[cq][0]; o4.y = o16[cq][1]; o4.z = o16[cq][2]; o4.w = o16[cq][3];
                    *(float4*)(wk + l*SW + cq*16 + dq*4) = o4;
                }
            }
            wave_sync();

            // proj partial: wq[l][c] = o[l][:] @ projW[c][hh*64:...]^T  (c = z-col)
            wgemm64<512>(wk + l*SW, proj_wl + hh*64, nullptr, wq + l*SW, dq);

            // reduce 4 wave partials into z (+bias on pass 0)
            __syncthreads();
#pragma unroll
            for (int it = 0; it < 4; ++it) {
                const int idx = tid + it*256;
                const int lr = idx >> 6, d = idx & 63;
                float s = pool[P_WQ + 0*1056 + lr*SW + d]
                        + pool[P_WQ + 1*1056 + lr*SW + d]
                        + pool[P_WQ + 2*1056 + lr*SW + d]
                        + pool[P_WQ + 3*1056 + lr*SW + d];
                if (pass == 0) s += proj_bl[d];
                s_z[lr*SA + d] += s;
            }
            __syncthreads();
        }

        // FF block: two 128-col passes through s_fh
        ln16x64(s_z, s_a, fln_g + layer*64, fln_b + layer*64, tid, false);
        __syncthreads();
#pragma unroll
        for (int p = 0; p < 2; ++p) {
            gemm_nd<2,64,64,SA,SX,2>(s_a, ff1_w + (size_t)layer*256*64 + (size_t)p*128*64,
                                     ff1_b + layer*256 + p*128, s_fh, tid, 2, false);
            __syncthreads();
            gemm_nd<1,128,256,SX,SA,4>(s_fh, ff2_w + (size_t)layer*64*256 + p*128,
                                       (p == 0) ? (ff2_b + layer*64) : nullptr, s_z, tid, 0, true);
            __syncthreads();
        }
    }

    // ---- h += z; mlp block on h (two 128-col passes) ----
#pragma unroll
    for (int it = 0; it < 4; ++it) {
        const int idx = tid + it*256;
        const int d = idx & 63, l = idx >> 6;
        s_h[l*SA + d] += s_z[l*SA + d];
    }
    __syncthreads();
    ln16x64(s_h, s_a, ln2_g, ln2_b, tid, false);
    __syncthreads();
#pragma unroll
    for (int p = 0; p < 2; ++p) {
        gemm_nd<2,64,64,SA,SX,2>(s_a, mlp1_w + (size_t)p*128*64, mlp1_b + p*128, s_fh, tid, 2, false);
        __syncthreads();
        gemm_nd<1,128,256,SX,SA,4>(s_fh, mlp2_w + p*128,
                                   (p == 0) ? mlp2_b : nullptr, s_h, tid, 0, true);
        __syncthreads();
    }

    // ---- concat [conv_x ; h^T] into s_cat [l][i] ----
#pragma unroll
    for (int it = 0; it < 8; ++it) {
        const int idx = tid + it*256;
        const int i = idx & 127, l = idx >> 7;
        s_cat[l*SX + i] = (i < 64) ? s_cx[i*16 + l] : s_h[l*SA + (i - 64)];
    }
    __syncthreads();

    // ---- c12 (128x128 matmul) -> s_res [l][c] ----
    gemm_nd<2,128,128,SX,SX,2>(s_cat, c12_w, c12_b, s_res, tid, 0, false);
    __syncthreads();

    // ---- out = x + res ----
    float* ob = out + (size_t)b * 2048;
#pragma unroll
    for (int it = 0; it < 8; ++it) {
        const int idx = tid + it*256;           // = c*16 + l
        const int c = idx >> 4, l = idx & 15;
        ob[idx] = xb[idx] + s_res[l*SX + c];
    }
}

extern "C" void kernel_launch(void* const* d_in, const int* in_sizes, int n_in,
                              void* d_out, int out_size, void* d_ws, size_t ws_size,
                              hipStream_t stream)
{
    const float* x      = (const float*)d_in[0];
    const float* c11_w  = (const float*)d_in[1];
    const float* c11_b  = (const float*)d_in[2];
    const float* c12_w  = (const float*)d_in[3];
    const float* c12_b  = (const float*)d_in[4];
    const float* lse1_w = (const float*)d_in[5];
    const float* lse1_b = (const float*)d_in[6];
    const float* lse2_w = (const float*)d_in[7];
    const float* lse2_b = (const float*)d_in[8];
    const float* ln1_g  = (const float*)d_in[9];
    const float* ln1_b  = (const float*)d_in[10];
    const float* ln2_g  = (const float*)d_in[11];
    const float* ln2_b  = (const float*)d_in[12];
    const float* mlp1_w = (const float*)d_in[13];
    const float* mlp1_b = (const float*)d_in[14];
    const float* mlp2_w = (const float*)d_in[15];
    const float* mlp2_b = (const float*)d_in[16];
    const float* aln_g  = (const float*)d_in[17];
    const float* aln_b  = (const float*)d_in[18];
    const float* qkv_w  = (const float*)d_in[19];
    const float* qkv_b  = (const float*)d_in[20];
    const float* proj_w = (const float*)d_in[21];
    const float* proj_b = (const float*)d_in[22];
    const float* relpos = (const float*)d_in[23];
    const float* fln_g  = (const float*)d_in[24];
    const float* fln_b  = (const float*)d_in[25];
    const float* ff1_w  = (const float*)d_in[26];
    const float* ff1_b  = (const float*)d_in[27];
    const float* ff2_w  = (const float*)d_in[28];
    const float* ff2_b  = (const float*)d_in[29];

    const int B = in_sizes[0] / (128 * 16);

    vse_fused<<<dim3(B), dim3(256), 0, stream>>>(
        x, c11_w, c11_b, c12_w, c12_b, lse1_w, lse1_b, lse2_w, lse2_b,
        ln1_g, ln1_b, ln2_g, ln2_b, mlp1_w, mlp1_b, mlp2_w, mlp2_b,
        aln_g, aln_b, qkv_w, qkv_b, proj_w, proj_b, relpos,
        fln_g, fln_b, ff1_w, ff1_b, ff2_w, ff2_b,
        (float*)d_out);
}

// Round 14
// 1549.596 us; speedup vs baseline: 1.1637x; 1.1637x over previous
//
#include <hip/hip_runtime.h>
#include <math.h>

#define SA 68    // stride (floats) for [16][64] buffers
#define SX 132   // stride for [16][128] buffers
#define SO 520   // stride for o_all [16][8*64+8]

// LDS pool offsets (floats)
#define P_H   0        // 1088 residual h
#define P_Z   1088     // 1088 transformer stream
#define P_A   2176     // 1088 LN out (alias: conv temp)
#define P_FH  3264     // 2112 c11-out / ff-half / res
#define P_CX  5376     // 1024 conv branch [c][l]
#define P_Q   6400     // 1088 q   (alias: x^T, concat span q..k)
#define P_K   7488     // 1088 k
#define P_V   8576     // 1088 v
#define P_OA  9664     // 8320 o_all [16][SO]
#define P_ATT 17984    // 272  att [16][17]
#define POOLF 18256    // 73024 B -> 2 blocks/CU

__device__ __forceinline__ float lrelu_f(float v){ return v > 0.f ? v : 0.01f*v; }
__device__ __forceinline__ float gelu_f(float v){ return 0.5f*v*(1.f + erff(v*0.70710678118654752f)); }

// Row-parallel GEMM: out[16][NB*64] = act(in @ W^T + bias), optional +=.
// Thread (rg = tid>>6, c0 = tid&63): rows rg*4..rg*4+3, col nb*64+c0.
// Weight loads: 1 float4 per (nb, k-quad) -> 4x fewer global loads than col-parallel;
// A-reads are wave-uniform LDS broadcasts (rg constant per wave).
template<int NB, int K, int WS, int IS, int OS, int UNR>
__device__ __forceinline__ void gemm_rc(const float* __restrict__ in,
                                        const float* __restrict__ W,
                                        const float* __restrict__ bias,
                                        float* __restrict__ outp,
                                        int tid, int act, bool accum)
{
    const int rg = tid >> 6;          // row group = wave id
    const int c0 = tid & 63;
    float acc[NB][4];
#pragma unroll
    for (int nb = 0; nb < NB; ++nb)
#pragma unroll
        for (int i = 0; i < 4; ++i) acc[nb][i] = 0.f;
    const float* inb = in + rg*4*IS;
#pragma unroll 1
    for (int k0 = 0; k0 < K; k0 += UNR*4) {
#pragma unroll
        for (int u = 0; u < UNR; ++u) {
            const int k = k0 + u*4;
            float4 w4[NB];
#pragma unroll
            for (int nb = 0; nb < NB; ++nb)
                w4[nb] = *(const float4*)(W + (size_t)(nb*64 + c0)*WS + k);
            float4 a4[4];
#pragma unroll
            for (int i = 0; i < 4; ++i)
                a4[i] = *(const float4*)(inb + i*IS + k);
#pragma unroll
            for (int nb = 0; nb < NB; ++nb)
#pragma unroll
                for (int i = 0; i < 4; ++i)
                    acc[nb][i] += a4[i].x*w4[nb].x + a4[i].y*w4[nb].y
                                + a4[i].z*w4[nb].z + a4[i].w*w4[nb].w;
        }
    }
#pragma unroll
    for (int nb = 0; nb < NB; ++nb) {
        const int c = nb*64 + c0;
        const float bv = bias ? bias[c] : 0.f;
#pragma unroll
        for (int i = 0; i < 4; ++i) {
            float v = acc[nb][i] + bv;
            if (act == 1) v = fmaxf(v, 0.f);
            else if (act == 2) v = gelu_f(v);
            float* o = outp + (rg*4 + i)*OS + c;
            if (accum) *o += v; else *o = v;
        }
    }
}

// LayerNorm 16x64 (stride SA); roll: src row r -> dst row (r+8)&15
__device__ __forceinline__ void ln16x64(const float* __restrict__ in,
                                        float* __restrict__ outb,
                                        const float* __restrict__ g, const float* __restrict__ bvec,
                                        int tid, bool roll)
{
    const int r = tid >> 4, c0 = (tid & 15) * 4;
    const float4 v = *(const float4*)(in + r*SA + c0);
    float s  = v.x + v.y + v.z + v.w;
    float sq = v.x*v.x + v.y*v.y + v.z*v.z + v.w*v.w;
#pragma unroll
    for (int m = 1; m < 16; m <<= 1) { s += __shfl_xor(s, m, 64); sq += __shfl_xor(sq, m, 64); }
    const float mean = s * (1.f/64.f);
    const float var  = sq * (1.f/64.f) - mean*mean;
    const float rstd = rsqrtf(var + 1e-5f);
    const int rd = roll ? ((r + 8) & 15) : r;
    const float4 gv = *(const float4*)(g + c0);
    const float4 bv = *(const float4*)(bvec + c0);
    float4 o;
    o.x = (v.x-mean)*rstd*gv.x + bv.x;
    o.y = (v.y-mean)*rstd*gv.y + bv.y;
    o.z = (v.z-mean)*rstd*gv.z + bv.z;
    o.w = (v.w-mean)*rstd*gv.w + bv.w;
    *(float4*)(outb + rd*SA + c0) = o;
}

// width-3 conv over L=16, zero pad, leaky-relu. layouts [ch][16].
__device__ __forceinline__ void conv3_lrelu(const float* __restrict__ in,
                                            float* __restrict__ outb,
                                            const float* __restrict__ w, const float* __restrict__ bias,
                                            int tid, int mode, float* __restrict__ cxbuf)
{
    const int o = tid >> 2, l0 = (tid & 3) * 4;
    float acc[4] = {0.f, 0.f, 0.f, 0.f};
    const float* wr0 = w + (size_t)o*64*3;
#pragma unroll 4
    for (int i = 0; i < 64; ++i) {
        const float* wr = wr0 + i*3;
        const float w0 = wr[0], w1 = wr[1], w2 = wr[2];
        const float* row = in + i*16 + l0;
        const float xm1 = (l0 == 0)  ? 0.f : row[-1];
        const float x0 = row[0], x1 = row[1], x2 = row[2], x3 = row[3];
        const float xp1 = (l0 == 12) ? 0.f : row[4];
        acc[0] += w0*xm1 + w1*x0 + w2*x1;
        acc[1] += w0*x0  + w1*x1 + w2*x2;
        acc[2] += w0*x1  + w1*x2 + w2*x3;
        acc[3] += w0*x2  + w1*x3 + w2*xp1;
    }
    const float bb = bias[o];
    if (mode == 0) {
#pragma unroll
        for (int j = 0; j < 4; ++j) outb[o*16 + l0 + j] = lrelu_f(acc[j] + bb);
    } else {
#pragma unroll
        for (int j = 0; j < 4; ++j) {
            float* p = cxbuf + o*16 + l0 + j;
            *p = lrelu_f(acc[j] + bb) + 2.f * (*p);
        }
    }
}

__global__ __launch_bounds__(256, 2) void vse_fused(
    const float* __restrict__ x,
    const float* __restrict__ c11_w, const float* __restrict__ c11_b,
    const float* __restrict__ c12_w, const float* __restrict__ c12_b,
    const float* __restrict__ lse1_w, const float* __restrict__ lse1_b,
    const float* __restrict__ lse2_w, const float* __restrict__ lse2_b,
    const float* __restrict__ ln1_g, const float* __restrict__ ln1_b,
    const float* __restrict__ ln2_g, const float* __restrict__ ln2_b,
    const float* __restrict__ mlp1_w, const float* __restrict__ mlp1_b,
    const float* __restrict__ mlp2_w, const float* __restrict__ mlp2_b,
    const float* __restrict__ aln_g, const float* __restrict__ aln_b,
    const float* __restrict__ qkv_w, const float* __restrict__ qkv_b,
    const float* __restrict__ proj_w, const float* __restrict__ proj_b,
    const float* __restrict__ relpos,
    const float* __restrict__ fln_g, const float* __restrict__ fln_b,
    const float* __restrict__ ff1_w, const float* __restrict__ ff1_b,
    const float* __restrict__ ff2_w, const float* __restrict__ ff2_b,
    float* __restrict__ out)
{
    __shared__ float pool[POOLF];
    float* const s_h   = pool + P_H;
    float* const s_z   = pool + P_Z;
    float* const s_a   = pool + P_A;
    float* const s_fh  = pool + P_FH;
    float* const s_cx  = pool + P_CX;
    float* const s_q   = pool + P_Q;
    float* const s_k   = pool + P_K;
    float* const s_v   = pool + P_V;
    float* const s_oa  = pool + P_OA;
    float* const s_att = pool + P_ATT;
    float* const s_xt  = s_q;     // x^T [16][SX] spans q..k (2112 <= 2176)
    float* const s_y   = s_fh;    // c11 out
    float* const s_t1  = s_a;     // conv temp [64][16]
    float* const s_cat = s_q;     // final concat
    float* const s_res = s_fh;    // final res

    const int tid = threadIdx.x;
    const int b = blockIdx.x;
    const float* xb = x + (size_t)b * 2048;

    // ---- load x transposed ----
#pragma unroll
    for (int it = 0; it < 8; ++it) {
        const int idx = tid + it*256;           // = c*16 + l
        const int c = idx >> 4, l = idx & 15;
        s_xt[l*SX + c] = xb[idx];
    }
    __syncthreads();

    // ---- c11 (128x128 matmul) + relu ----
    gemm_rc<2,128,128,SX,SX,4>(s_xt, c11_w, c11_b, s_y, tid, 1, false);
    __syncthreads();

    // ---- split: conv_x [c][l], h [l][d] ----
#pragma unroll
    for (int it = 0; it < 4; ++it) {
        const int idx = tid + it*256;
        const int i = idx & 63, l = idx >> 6;
        s_cx[i*16 + l] = s_y[l*SX + i];
        s_h [l*SA + i] = s_y[l*SX + 64 + i];
    }
    __syncthreads();

    // ---- conv branch ----
    conv3_lrelu(s_cx, s_t1, lse1_w, lse1_b, tid, 0, nullptr);
    __syncthreads();
    conv3_lrelu(s_t1, nullptr, lse2_w, lse2_b, tid, 1, s_cx);
    __syncthreads();

    // ---- z = LN(h, ln1) ----
    ln16x64(s_h, s_z, ln1_g, ln1_b, tid, false);
    __syncthreads();

    // ---- transformer layers ----
    for (int layer = 0; layer < 2; ++layer) {
        const float* qkv_wl  = qkv_w + (size_t)layer * 98304;
        const float* qkv_bl  = qkv_b + layer * 1536;
        const float* proj_wl = proj_w + (size_t)layer * 32768;
        const float* proj_bl = proj_b + layer * 64;
        const float* rel_l   = relpos + layer * 8 * 49;

        // a = roll(LN(z, aln), -8)
        ln16x64(s_z, s_a, aln_g + layer*64, aln_b + layer*64, tid, true);
        __syncthreads();

        for (int hh = 0; hh < 8; ++hh) {
            gemm_rc<1,64,64,SA,SA,8>(s_a, qkv_wl + (size_t)(hh*64)*64,        qkv_bl + hh*64,        s_q, tid, 0, false);
            gemm_rc<1,64,64,SA,SA,8>(s_a, qkv_wl + (size_t)(512 + hh*64)*64,  qkv_bl + 512 + hh*64,  s_k, tid, 0, false);
            gemm_rc<1,64,64,SA,SA,8>(s_a, qkv_wl + (size_t)(1024 + hh*64)*64, qkv_bl + 1024 + hh*64, s_v, tid, 0, false);
            __syncthreads();

            {   // dots + relpos + mask + softmax (thread (i,j) holds one score)
                const int i = tid >> 4, j = tid & 15;
                const float* qi = s_q + i*SA;
                const float* kj = s_k + j*SA;
                float dot = 0.f;
#pragma unroll 4
                for (int d0 = 0; d0 < 64; d0 += 4) {
                    const float4 qv = *(const float4*)(qi + d0);
                    const float4 kv = *(const float4*)(kj + d0);
                    dot += qv.x*kv.x + qv.y*kv.y + qv.z*kv.z + qv.w*kv.w;
                }
                float val = dot * 0.125f
                          + rel_l[hh*49 + ((i>>2) - (j>>2) + 3)*7 + ((i&3) - (j&3) + 3)];
                const bool masked = ((hh >= 6) && (((i>>2) < 2) != ((j>>2) < 2)))
                                 || ((hh & 1) && (((i&3) < 2) != ((j&3) < 2)));
                if (masked) val = -1e9f;
                float mx = val;
#pragma unroll
                for (int m = 1; m < 16; m <<= 1) mx = fmaxf(mx, __shfl_xor(mx, m, 64));
                const float e = expf(val - mx);
                float ssum = e;
#pragma unroll
                for (int m = 1; m < 16; m <<= 1) ssum += __shfl_xor(ssum, m, 64);
                s_att[i*17 + j] = e / ssum;
            }
            __syncthreads();

            {   // o_all[:, hh*64:] = attn @ v
                const int l = tid & 15, dq = tid >> 4;
                float a0 = 0.f, a1 = 0.f, a2 = 0.f, a3 = 0.f;
#pragma unroll 4
                for (int j = 0; j < 16; ++j) {
                    const float at = s_att[l*17 + j];
                    const float4 v4 = *(const float4*)(s_v + j*SA + dq*4);
                    a0 += at*v4.x; a1 += at*v4.y; a2 += at*v4.z; a3 += at*v4.w;
                }
                float* op = s_oa + l*SO + hh*64 + dq*4;
                op[0] = a0; op[1] = a1; op[2] = a2; op[3] = a3;
            }
            __syncthreads();
        }

        // z += o_all @ proj^T + bias  (single K=512 GEMM)
        gemm_rc<1,512,512,SO,SA,8>(s_oa, proj_wl, proj_bl, s_z, tid, 0, true);
        __syncthreads();

        // FF block: two 128-col passes through s_fh
        ln16x64(s_z, s_a, fln_g + layer*64, fln_b + layer*64, tid, false);
        __syncthreads();
#pragma unroll
        for (int p = 0; p < 2; ++p) {
            gemm_rc<2,64,64,SA,SX,4>(s_a, ff1_w + (size_t)layer*256*64 + (size_t)p*128*64,
                                     ff1_b + layer*256 + p*128, s_fh, tid, 2, false);
            __syncthreads();
            gemm_rc<1,128,256,SX,SA,8>(s_fh, ff2_w + (size_t)layer*64*256 + p*128,
                                       (p == 0) ? (ff2_b + layer*64) : nullptr, s_z, tid, 0, true);
            __syncthreads();
        }
    }

    // ---- h += z; mlp block on h (two 128-col passes) ----
#pragma unroll
    for (int it = 0; it < 4; ++it) {
        const int idx = tid + it*256;
        const int d = idx & 63, l = idx >> 6;
        s_h[l*SA + d] += s_z[l*SA + d];
    }
    __syncthreads();
    ln16x64(s_h, s_a, ln2_g, ln2_b, tid, false);
    __syncthreads();
#pragma unroll
    for (int p = 0; p < 2; ++p) {
        gemm_rc<2,64,64,SA,SX,4>(s_a, mlp1_w + (size_t)p*128*64, mlp1_b + p*128, s_fh, tid, 2, false);
        __syncthreads();
        gemm_rc<1,128,256,SX,SA,8>(s_fh, mlp2_w + p*128,
                                   (p == 0) ? mlp2_b : nullptr, s_h, tid, 0, true);
        __syncthreads();
    }

    // ---- concat [conv_x ; h^T] into s_cat [l][i] ----
#pragma unroll
    for (int it = 0; it < 8; ++it) {
        const int idx = tid + it*256;
        const int i = idx & 127, l = idx >> 7;
        s_cat[l*SX + i] = (i < 64) ? s_cx[i*16 + l] : s_h[l*SA + (i - 64)];
    }
    __syncthreads();

    // ---- c12 (128x128 matmul) -> s_res [l][c] ----
    gemm_rc<2,128,128,SX,SX,4>(s_cat, c12_w, c12_b, s_res, tid, 0, false);
    __syncthreads();

    // ---- out = x + res ----
    float* ob = out + (size_t)b * 2048;
#pragma unroll
    for (int it = 0; it < 8; ++it) {
        const int idx = tid + it*256;           // = c*16 + l
        const int c = idx >> 4, l = idx & 15;
        ob[idx] = xb[idx] + s_res[l*SX + c];
    }
}

extern "C" void kernel_launch(void* const* d_in, const int* in_sizes, int n_in,
                              void* d_out, int out_size, void* d_ws, size_t ws_size,
                              hipStream_t stream)
{
    const float* x      = (const float*)d_in[0];
    const float* c11_w  = (const float*)d_in[1];
    const float* c11_b  = (const float*)d_in[2];
    const float* c12_w  = (const float*)d_in[3];
    const float* c12_b  = (const float*)d_in[4];
    const float* lse1_w = (const float*)d_in[5];
    const float* lse1_b = (const float*)d_in[6];
    const float* lse2_w = (const float*)d_in[7];
    const float* lse2_b = (const float*)d_in[8];
    const float* ln1_g  = (const float*)d_in[9];
    const float* ln1_b  = (const float*)d_in[10];
    const float* ln2_g  = (const float*)d_in[11];
    const float* ln2_b  = (const float*)d_in[12];
    const float* mlp1_w = (const float*)d_in[13];
    const float* mlp1_b = (const float*)d_in[14];
    const float* mlp2_w = (const float*)d_in[15];
    const float* mlp2_b = (const float*)d_in[16];
    const float* aln_g  = (const float*)d_in[17];
    const float* aln_b  = (const float*)d_in[18];
    const float* qkv_w  = (const float*)d_in[19];
    const float* qkv_b  = (const float*)d_in[20];
    const float* proj_w = (const float*)d_in[21];
    const float* proj_b = (const float*)d_in[22];
    const float* relpos = (const float*)d_in[23];
    const float* fln_g  = (const float*)d_in[24];
    const float* fln_b  = (const float*)d_in[25];
    const float* ff1_w  = (const float*)d_in[26];
    const float* ff1_b  = (const float*)d_in[27];
    const float* ff2_w  = (const float*)d_in[28];
    const float* ff2_b  = (const float*)d_in[29];

    const int B = in_sizes[0] / (128 * 16);

    vse_fused<<<dim3(B), dim3(256), 0, stream>>>(
        x, c11_w, c11_b, c12_w, c12_b, lse1_w, lse1_b, lse2_w, lse2_b,
        ln1_g, ln1_b, ln2_g, ln2_b, mlp1_w, mlp1_b, mlp2_w, mlp2_b,
        aln_g, aln_b, qkv_w, qkv_b, proj_w, proj_b, relpos,
        fln_g, fln_b, ff1_w, ff1_b, ff2_w, ff2_b,
        (float*)d_out);
}